// Round 7
// baseline (709.540 us; speedup 1.0000x reference)
//
#include <hip/hip_runtime.h>
#include <hip/hip_bf16.h>
#include <stdint.h>

#define N_PTS 500000
#define NVOX  65536
#define K1_TILES ((N_PTS + 127) / 128)   // 3907
#define K3_TILES ((N_PTS + 127) / 128)   // 3907  (M=128 per block, 512 threads)

typedef __attribute__((ext_vector_type(8))) short bf16x8;   // 8 x bf16 (4 VGPRs)
typedef __attribute__((ext_vector_type(4))) float f32x4;    // MFMA accumulator

__device__ inline unsigned short f2bf(float f) {
    union { float f; unsigned int u; } v; v.f = f;
    unsigned int r = v.u + 0x7FFFu + ((v.u >> 16) & 1u);   // RNE
    return (unsigned short)(r >> 16);
}
__device__ inline float bf2f(unsigned short h) {
    return __uint_as_float((unsigned int)h << 16);
}

// --------- fused weight prep: all transposes into one contiguous region ----
#define WOFF_W1T   0
#define WOFF_W2T   2048
#define WOFF_WV1T  10240
#define WOFF_W3AT  26624
#define WOFF_W3BT  59392
#define WOFF_W4T   92160
#define WOFF_WV2T  157696
#define W_TOTAL    223232

__global__ void prep_all(const float* __restrict__ W1, const float* __restrict__ W2,
                         const float* __restrict__ Wv1, const float* __restrict__ W3,
                         const float* __restrict__ W4, const float* __restrict__ Wv2,
                         unsigned short* __restrict__ dst) {
    int i = blockIdx.x * 256 + threadIdx.x;
    if (i >= W_TOTAL) return;
    int o = i;
    if (o < 2048) {                       // W1T: [64][32], pad k
        int n = o >> 5, k = o & 31;
        dst[i] = (k < 6) ? f2bf(W1[k * 64 + n]) : (unsigned short)0;
    } else if ((o -= 2048) < 8192) {      // W2T: K=64 Nn=128
        int n = o >> 6, k = o & 63;
        dst[i] = f2bf(W2[k * 128 + n]);
    } else if ((o -= 8192) < 16384) {     // Wv1T: K=128 Nn=128
        int n = o >> 7, k = o & 127;
        dst[i] = f2bf(Wv1[k * 128 + n]);
    } else if ((o -= 16384) < 32768) {    // W3aT: K=128 Nn=256 k0=0
        int n = o >> 7, k = o & 127;
        dst[i] = f2bf(W3[k * 256 + n]);
    } else if ((o -= 32768) < 32768) {    // W3bT: K=128 Nn=256 k0=128
        int n = o >> 7, k = o & 127;
        dst[i] = f2bf(W3[(k + 128) * 256 + n]);
    } else if ((o -= 32768) < 65536) {    // W4T: K=256 Nn=256
        int n = o >> 8, k = o & 255;
        dst[i] = f2bf(W4[k * 256 + n]);
    } else {                              // Wv2T
        o -= 65536;
        int n = o >> 8, k = o & 255;
        dst[i] = f2bf(Wv2[k * 256 + n]);
    }
}

// ------------------------- counting sort by voxel --------------------------
__global__ void s_hist(const int* __restrict__ idx, unsigned int* __restrict__ counts) {
    int p = blockIdx.x * 256 + threadIdx.x;
    if (p < N_PTS) atomicAdd(&counts[idx[p]], 1u);
}

__global__ __launch_bounds__(1024) void s_scan(const unsigned int* __restrict__ counts,
                                               unsigned int* __restrict__ cursor) {
    __shared__ unsigned int sPart[1024];
    int t = threadIdx.x;
    unsigned int sum = 0;
    #pragma unroll 8
    for (int i = 0; i < 64; i++) sum += counts[t * 64 + i];
    sPart[t] = sum;
    __syncthreads();
    for (int d = 1; d < 1024; d <<= 1) {
        unsigned int add = (t >= d) ? sPart[t - d] : 0u;
        __syncthreads();
        sPart[t] += add;
        __syncthreads();
    }
    unsigned int run = (t == 0) ? 0u : sPart[t - 1];
    #pragma unroll 8
    for (int i = 0; i < 64; i++) {
        cursor[t * 64 + i] = run;
        run += counts[t * 64 + i];
    }
}

__global__ void s_scatter(const int* __restrict__ idx, unsigned int* __restrict__ cursor,
                          int* __restrict__ order, int* __restrict__ svox) {
    int p = blockIdx.x * 256 + threadIdx.x;
    if (p < N_PTS) {
        int v = idx[p];
        unsigned int pos = atomicAdd(&cursor[v], 1u);
        order[pos] = p;
        svox[pos] = v;
    }
}

// ---------------------------------------------------------------------------
// K1 (sorted): per 128-sorted-point tile: feat1, feat2 via MFMA; segmented
// max over voxel runs in LDS; interior segments use plain stores (exclusive
// ownership under sort), boundary segments atomicMax -> vox1acc.
// ---------------------------------------------------------------------------
__global__ __launch_bounds__(256) void k1_points(
    const float* __restrict__ inp,
    const int* __restrict__ order, const int* __restrict__ svox,
    const unsigned short* __restrict__ W1T, const float* __restrict__ b1,
    const unsigned short* __restrict__ W2T, const float* __restrict__ b2,
    unsigned int* __restrict__ vox1acc)      // [V][128] fp32-as-uint (zeroed)
{
    __shared__ __align__(16) char sBuf[32 * 1024];
    __shared__ float sb1[64];
    __shared__ float sb2[128];
    __shared__ int   sVox[128];
    char* sIn = sBuf;                // [128][32] bf16, row 64B,  swz (m&3)<<4
    char* sF1 = sBuf + 8 * 1024;     // [128][64] bf16, row 128B, swz (m&7)<<4
    char* sF2 = sBuf;                // [128][128] bf16, row 256B, swz (m&7)<<4
    const f32x4 fzero = {0.f, 0.f, 0.f, 0.f};
    int tid = threadIdx.x;
    int pbase = blockIdx.x * 128;
    if (tid < 64)       sb1[tid] = b1[tid];
    else if (tid < 192) sb2[tid - 64] = b2[tid - 64];
    if (tid < 128) {
        int i = pbase + tid;
        int pt = -1, v = -1;
        if (i < N_PTS) { pt = order[i]; v = svox[i]; }
        sVox[tid] = v;
        uint4 g0 = {0u, 0u, 0u, 0u};
        if (pt >= 0) {
            const float* x = inp + (size_t)pt * 6;
            g0.x = (unsigned)f2bf(x[0]) | ((unsigned)f2bf(x[1]) << 16);
            g0.y = (unsigned)f2bf(x[2]) | ((unsigned)f2bf(x[3]) << 16);
            g0.z = (unsigned)f2bf(x[4]) | ((unsigned)f2bf(x[5]) << 16);
        }
        int swz = (tid & 3) << 4;
        char* row = sIn + tid * 64;
        uint4 z = {0u, 0u, 0u, 0u};
        *(uint4*)(row + (0  ^ swz)) = g0;
        *(uint4*)(row + (16 ^ swz)) = z;
        *(uint4*)(row + (32 ^ swz)) = z;
        *(uint4*)(row + (48 ^ swz)) = z;
    }
    __syncthreads();
    int wave = tid >> 6, lane = tid & 63, quad = lane >> 4, l16 = lane & 15;

    // GEMM1: [128][32]@[32][64]
    {
        f32x4 acc1[8];
        #pragma unroll
        for (int mt = 0; mt < 8; mt++) acc1[mt] = fzero;
        int n = wave * 16 + l16;
        bf16x8 b = *(const bf16x8*)(W1T + n * 32 + quad * 8);
        #pragma unroll
        for (int mt = 0; mt < 8; mt++) {
            int m = mt * 16 + l16;
            bf16x8 a = *(const bf16x8*)(sIn + m * 64 + ((quad * 16) ^ ((m & 3) << 4)));
            acc1[mt] = __builtin_amdgcn_mfma_f32_16x16x32_bf16(a, b, acc1[mt], 0, 0, 0);
        }
        float bias = sb1[n];
        #pragma unroll
        for (int mt = 0; mt < 8; mt++)
            #pragma unroll
            for (int r = 0; r < 4; r++) {
                int m = mt * 16 + quad * 4 + r;
                float v = fmaxf(acc1[mt][r] + bias, 0.f);
                *(unsigned short*)(sF1 + m * 128 + ((2 * n) ^ ((m & 7) << 4))) = f2bf(v);
            }
    }
    __syncthreads();
    // GEMM2: [128][64]@[64][128]
    f32x4 acc2[2][8];
    #pragma unroll
    for (int j = 0; j < 2; j++)
        #pragma unroll
        for (int mt = 0; mt < 8; mt++) acc2[j][mt] = fzero;
    #pragma unroll
    for (int kt = 0; kt < 2; kt++) {
        bf16x8 b0 = *(const bf16x8*)(W2T + ((wave * 2 + 0) * 16 + l16) * 64 + kt * 32 + quad * 8);
        bf16x8 b1 = *(const bf16x8*)(W2T + ((wave * 2 + 1) * 16 + l16) * 64 + kt * 32 + quad * 8);
        #pragma unroll
        for (int mt = 0; mt < 8; mt++) {
            int m = mt * 16 + l16;
            bf16x8 a = *(const bf16x8*)(sF1 + m * 128 + ((kt * 64 + quad * 16) ^ ((m & 7) << 4)));
            acc2[0][mt] = __builtin_amdgcn_mfma_f32_16x16x32_bf16(a, b0, acc2[0][mt], 0, 0, 0);
            acc2[1][mt] = __builtin_amdgcn_mfma_f32_16x16x32_bf16(a, b1, acc2[1][mt], 0, 0, 0);
        }
    }
    __syncthreads();   // all sIn/sF1 reads done before sF2 overwrite
    #pragma unroll
    for (int j = 0; j < 2; j++) {
        int n = (wave * 2 + j) * 16 + l16;
        float bias = sb2[n];
        #pragma unroll
        for (int mt = 0; mt < 8; mt++)
            #pragma unroll
            for (int r = 0; r < 4; r++) {
                int m = mt * 16 + quad * 4 + r;
                float v = fmaxf(acc2[j][mt][r] + bias, 0.f);
                *(unsigned short*)(sF2 + m * 256 + ((2 * n) ^ ((m & 7) << 4))) = f2bf(v);
            }
    }
    __syncthreads();
    // segmented max walk; interior segments -> plain store
    {
        int c = tid & 127, r0 = (tid >> 7) * 64;
        int cur = -1; float vmax = 0.f; int segStart = r0;
        for (int r = r0; r < r0 + 64; r++) {
            int v = sVox[r];
            float f = bf2f(*(const unsigned short*)(sF2 + r * 256 + ((2 * c) ^ ((r & 7) << 4))));
            if (v != cur) {
                if (cur >= 0) {
                    if (segStart > r0)
                        vox1acc[(size_t)cur * 128 + c] = __float_as_uint(vmax);
                    else
                        atomicMax(vox1acc + (size_t)cur * 128 + c, __float_as_uint(vmax));
                }
                cur = v; vmax = f; segStart = r;
            } else vmax = fmaxf(vmax, f);
        }
        if (cur >= 0)
            atomicMax(vox1acc + (size_t)cur * 128 + c, __float_as_uint(vmax));
    }
}

// ---------------------------------------------------------------------------
// kvox2 (fused voxel chain): voxA = relu(vox1acc@Wv1+bv1);
// voxB = voxA@W3a (no bias/relu — b3 added in k3). voxB written IN-PLACE over
// vox1acc (block reads its 64 rows to LDS first; same byte range: 512 B/row).
// ---------------------------------------------------------------------------
__global__ __launch_bounds__(256) void kvox2(
    const float* __restrict__ in, const unsigned short* __restrict__ Wv1T,
    const float* __restrict__ bv1, const unsigned short* __restrict__ W3aT,
    unsigned short* __restrict__ voxB)     // [V][256] bf16, aliases `in`
{
    __shared__ __align__(16) char sA[64 * 256];   // [64][128] bf16 input
    __shared__ __align__(16) char sB[64 * 256];   // [64][128] bf16 voxA
    __shared__ float sb[128];
    const f32x4 fzero = {0.f, 0.f, 0.f, 0.f};
    int tid = threadIdx.x;
    int vb = blockIdx.x * 64;
    if (tid < 128) sb[tid] = bv1[tid];
    #pragma unroll
    for (int it = 0; it < 8; it++) {
        int i = tid + 256 * it;
        int m = i >> 5, kq = i & 31;
        float4 f = ((const float4*)(in + (size_t)(vb + m) * 128))[kq];
        uint2 p;
        p.x = (unsigned)f2bf(f.x) | ((unsigned)f2bf(f.y) << 16);
        p.y = (unsigned)f2bf(f.z) | ((unsigned)f2bf(f.w) << 16);
        *(uint2*)(sA + m * 256 + ((8 * kq) ^ ((m & 7) << 4))) = p;
    }
    __syncthreads();
    int wave = tid >> 6, lane = tid & 63, quad = lane >> 4, l16 = lane & 15;
    // GEMM A: voxA = relu([64][128]@[128][128] + bv1)
    {
        f32x4 acc[2][4];
        #pragma unroll
        for (int j = 0; j < 2; j++)
            #pragma unroll
            for (int mt = 0; mt < 4; mt++) acc[j][mt] = fzero;
        #pragma unroll
        for (int kt = 0; kt < 4; kt++) {
            bf16x8 a[4];
            #pragma unroll
            for (int mt = 0; mt < 4; mt++) {
                int m = mt * 16 + l16;
                a[mt] = *(const bf16x8*)(sA + m * 256 + ((kt * 64 + quad * 16) ^ ((m & 7) << 4)));
            }
            #pragma unroll
            for (int j = 0; j < 2; j++) {
                int n = (wave * 2 + j) * 16 + l16;
                bf16x8 b = *(const bf16x8*)(Wv1T + n * 128 + kt * 32 + quad * 8);
                #pragma unroll
                for (int mt = 0; mt < 4; mt++)
                    acc[j][mt] = __builtin_amdgcn_mfma_f32_16x16x32_bf16(a[mt], b, acc[j][mt], 0, 0, 0);
            }
        }
        #pragma unroll
        for (int j = 0; j < 2; j++) {
            int n = (wave * 2 + j) * 16 + l16;
            float bi = sb[n];
            #pragma unroll
            for (int mt = 0; mt < 4; mt++)
                #pragma unroll
                for (int r = 0; r < 4; r++) {
                    int m = mt * 16 + quad * 4 + r;
                    float v = fmaxf(acc[j][mt][r] + bi, 0.f);
                    *(unsigned short*)(sB + m * 256 + ((2 * n) ^ ((m & 7) << 4))) = f2bf(v);
                }
        }
    }
    __syncthreads();
    // GEMM B: voxB = voxA@[128][256]; no bias/relu
    {
        f32x4 acc[4][4];
        #pragma unroll
        for (int j = 0; j < 4; j++)
            #pragma unroll
            for (int mt = 0; mt < 4; mt++) acc[j][mt] = fzero;
        #pragma unroll
        for (int kt = 0; kt < 4; kt++) {
            bf16x8 a[4];
            #pragma unroll
            for (int mt = 0; mt < 4; mt++) {
                int m = mt * 16 + l16;
                a[mt] = *(const bf16x8*)(sB + m * 256 + ((kt * 64 + quad * 16) ^ ((m & 7) << 4)));
            }
            #pragma unroll
            for (int j = 0; j < 4; j++) {
                int n = (wave * 4 + j) * 16 + l16;
                bf16x8 b = *(const bf16x8*)(W3aT + n * 128 + kt * 32 + quad * 8);
                #pragma unroll
                for (int mt = 0; mt < 4; mt++)
                    acc[j][mt] = __builtin_amdgcn_mfma_f32_16x16x32_bf16(a[mt], b, acc[j][mt], 0, 0, 0);
            }
        }
        #pragma unroll
        for (int j = 0; j < 4; j++) {
            int n = (wave * 4 + j) * 16 + l16;
            #pragma unroll
            for (int mt = 0; mt < 4; mt++)
                #pragma unroll
                for (int r = 0; r < 4; r++) {
                    int m = mt * 16 + quad * 4 + r;
                    voxB[(size_t)(vb + m) * 256 + n] = f2bf(acc[j][mt][r]);
                }
        }
    }
}

// ---------------------------------------------------------------------------
// K3 v7: 512 threads (8 waves), M=128, full-M phases (8 syncs), spill-free:
//  - no register-resident gather (dedicated short phase after GEMM3')
//  - B-fragment prefetch (kt+1 loaded while kt MFMAs) in GEMM3'/GEMM4
//  - segmax interior segments -> plain store
// Peak regs ~= 64 AGPR (acc[2][8]) + ~40 VGPR < 128 cap at (512,4).
// ---------------------------------------------------------------------------
__global__ __launch_bounds__(512, 4) void k3_heavy(
    const float* __restrict__ inp,
    const int* __restrict__ order, const int* __restrict__ svox,
    const unsigned short* __restrict__ W1T, const float* __restrict__ b1,
    const unsigned short* __restrict__ W2T, const float* __restrict__ b2,
    const unsigned short* __restrict__ voxB,     // [V][256] bf16
    const unsigned short* __restrict__ W3bT, const float* __restrict__ b3,
    const unsigned short* __restrict__ W4T, const float* __restrict__ b4,
    unsigned int* __restrict__ vox2acc)          // [V][256] fp32-as-uint (zeroed)
{
    __shared__ __align__(16) char sBuf[64 * 1024];
    __shared__ float sb1[64];
    __shared__ float sb2[128];
    __shared__ float sb3[256];
    __shared__ float sb4[256];
    __shared__ int   sVox[128];
    char* sF2 = sBuf;                 // [128][128] bf16, row 256B  (dies after GEMM3')
    char* sF1 = sBuf + 32 * 1024;     // [128][64]  bf16, row 128B  (phase 1-2)
    char* sIn = sBuf + 56 * 1024;     // [128][32]  bf16, row 64B   (phase 0-1)
    char* sP  = sBuf;                 // [128][256] bf16, row 512B  (gather onward)
    const f32x4 fzero = {0.f, 0.f, 0.f, 0.f};
    int tid = threadIdx.x;
    int pbase = blockIdx.x * 128;
    if (tid < 256)      { sb3[tid] = b3[tid]; sb4[tid] = b4[tid]; }
    else if (tid < 320) sb1[tid - 256] = b1[tid - 256];
    else if (tid < 448) sb2[tid - 320] = b2[tid - 320];
    if (tid < 128) {
        int i = pbase + tid;
        int pt = -1, v = -1;
        if (i < N_PTS) { pt = order[i]; v = svox[i]; }
        sVox[tid] = v;
        uint4 g0 = {0u, 0u, 0u, 0u};
        if (pt >= 0) {
            const float* x = inp + (size_t)pt * 6;
            g0.x = (unsigned)f2bf(x[0]) | ((unsigned)f2bf(x[1]) << 16);
            g0.y = (unsigned)f2bf(x[2]) | ((unsigned)f2bf(x[3]) << 16);
            g0.z = (unsigned)f2bf(x[4]) | ((unsigned)f2bf(x[5]) << 16);
        }
        int swz = (tid & 3) << 4;
        char* row = sIn + tid * 64;
        uint4 z = {0u, 0u, 0u, 0u};
        *(uint4*)(row + (0  ^ swz)) = g0;
        *(uint4*)(row + (16 ^ swz)) = z;
        *(uint4*)(row + (32 ^ swz)) = z;
        *(uint4*)(row + (48 ^ swz)) = z;
    }
    __syncthreads();
    int wave = tid >> 6, lane = tid & 63, quad = lane >> 4, l16 = lane & 15;
    int n0 = (wave * 2) * 16 + l16;
    int n1 = n0 + 16;

    // GEMM1: feat1 = relu([128][32]@[32][64] + b1) -> sF1
    // wave handles m-tiles (wave&1)*4..+3, n-tile (wave>>1)
    {
        f32x4 acc1[4];
        #pragma unroll
        for (int mt = 0; mt < 4; mt++) acc1[mt] = fzero;
        int mt0 = (wave & 1) * 4;
        int n = (wave >> 1) * 16 + l16;
        bf16x8 b = *(const bf16x8*)(W1T + n * 32 + quad * 8);
        #pragma unroll
        for (int mt = 0; mt < 4; mt++) {
            int m = (mt0 + mt) * 16 + l16;
            bf16x8 a = *(const bf16x8*)(sIn + m * 64 + ((quad * 16) ^ ((m & 3) << 4)));
            acc1[mt] = __builtin_amdgcn_mfma_f32_16x16x32_bf16(a, b, acc1[mt], 0, 0, 0);
        }
        float bias = sb1[n];
        #pragma unroll
        for (int mt = 0; mt < 4; mt++)
            #pragma unroll
            for (int r = 0; r < 4; r++) {
                int m = (mt0 + mt) * 16 + quad * 4 + r;
                float v = fmaxf(acc1[mt][r] + bias, 0.f);
                *(unsigned short*)(sF1 + m * 128 + ((2 * n) ^ ((m & 7) << 4))) = f2bf(v);
            }
    }
    __syncthreads();
    // GEMM2: feat2 = relu([128][64]@[64][128] + b2) -> sF2 (disjoint region)
    {
        f32x4 acc2[8];
        #pragma unroll
        for (int mt = 0; mt < 8; mt++) acc2[mt] = fzero;
        int n = wave * 16 + l16;
        #pragma unroll
        for (int kt = 0; kt < 2; kt++) {
            bf16x8 b = *(const bf16x8*)(W2T + n * 64 + kt * 32 + quad * 8);
            #pragma unroll
            for (int mt = 0; mt < 8; mt++) {
                int m = mt * 16 + l16;
                bf16x8 a = *(const bf16x8*)(sF1 + m * 128 + ((kt * 64 + quad * 16) ^ ((m & 7) << 4)));
                acc2[mt] = __builtin_amdgcn_mfma_f32_16x16x32_bf16(a, b, acc2[mt], 0, 0, 0);
            }
        }
        float bias = sb2[n];
        #pragma unroll
        for (int mt = 0; mt < 8; mt++)
            #pragma unroll
            for (int r = 0; r < 4; r++) {
                int m = mt * 16 + quad * 4 + r;
                float v = fmaxf(acc2[mt][r] + bias, 0.f);
                *(unsigned short*)(sF2 + m * 256 + ((2 * n) ^ ((m & 7) << 4))) = f2bf(v);
            }
    }
    __syncthreads();   // sF1/sIn dead; sF2 complete

    // GEMM3': [128][128] @ [128][256]; wave owns n-tiles 2w,2w+1, 8 m-tiles.
    // B prefetched one kt ahead.
    f32x4 acc[2][8];
    #pragma unroll
    for (int j = 0; j < 2; j++)
        #pragma unroll
        for (int mt = 0; mt < 8; mt++) acc[j][mt] = fzero;
    {
        bf16x8 b0 = *(const bf16x8*)(W3bT + n0 * 128 + quad * 8);
        bf16x8 b1 = *(const bf16x8*)(W3bT + n1 * 128 + quad * 8);
        #pragma unroll 1
        for (int kt = 0; kt < 4; kt++) {
            bf16x8 cb0 = b0, cb1 = b1;
            if (kt < 3) {
                b0 = *(const bf16x8*)(W3bT + n0 * 128 + (kt + 1) * 32 + quad * 8);
                b1 = *(const bf16x8*)(W3bT + n1 * 128 + (kt + 1) * 32 + quad * 8);
            }
            #pragma unroll
            for (int mt = 0; mt < 8; mt++) {
                int m = mt * 16 + l16;
                bf16x8 a = *(const bf16x8*)(sF2 + m * 256 + ((kt * 64 + quad * 16) ^ ((m & 7) << 4)));
                acc[0][mt] = __builtin_amdgcn_mfma_f32_16x16x32_bf16(a, cb0, acc[0][mt], 0, 0, 0);
                acc[1][mt] = __builtin_amdgcn_mfma_f32_16x16x32_bf16(a, cb1, acc[1][mt], 0, 0, 0);
            }
        }
    }
    __syncthreads();   // sF2 reads complete — arena becomes sP
    // gather voxB rows -> sP [128][256] (sorted -> dedup, L2 hits); 2 batches of 4
    #pragma unroll
    for (int bat = 0; bat < 2; bat++) {
        uint4 g[4];
        #pragma unroll
        for (int it = 0; it < 4; it++) {
            int i = tid + 512 * (bat * 4 + it);
            int m = i >> 5;
            int vv = sVox[m];
            uint4 val = {0u, 0u, 0u, 0u};
            if (vv >= 0)
                val = ((const uint4*)(voxB + (size_t)vv * 256))[i & 31];
            g[it] = val;
        }
        #pragma unroll
        for (int it = 0; it < 4; it++) {
            int i = tid + 512 * (bat * 4 + it);
            int m = i >> 5, c = i & 31;
            *(uint4*)(sP + m * 512 + ((c * 16) ^ ((m & 7) << 4))) = g[it];
        }
    }
    __syncthreads();
    // feat4 = relu(acc + b3 + voxpart) -> sP in-place
    #pragma unroll
    for (int j = 0; j < 2; j++) {
        int n = (wave * 2 + j) * 16 + l16;
        float bias = sb3[n];
        #pragma unroll
        for (int mt = 0; mt < 8; mt++)
            #pragma unroll
            for (int r = 0; r < 4; r++) {
                int m = mt * 16 + quad * 4 + r;
                char* p = sP + m * 512 + ((2 * n) ^ ((m & 7) << 4));
                float vox = bf2f(*(const unsigned short*)p);
                float v = fmaxf(acc[j][mt][r] + bias + vox, 0.f);
                *(unsigned short*)p = f2bf(v);
            }
    }
    __syncthreads();
    #pragma unroll
    for (int j = 0; j < 2; j++)
        #pragma unroll
        for (int mt = 0; mt < 8; mt++) acc[j][mt] = fzero;
    // GEMM4: [128][256] @ [256][256]; B prefetched one kt ahead
    {
        bf16x8 b0 = *(const bf16x8*)(W4T + n0 * 256 + quad * 8);
        bf16x8 b1 = *(const bf16x8*)(W4T + n1 * 256 + quad * 8);
        #pragma unroll 1
        for (int kt = 0; kt < 8; kt++) {
            bf16x8 cb0 = b0, cb1 = b1;
            if (kt < 7) {
                b0 = *(const bf16x8*)(W4T + n0 * 256 + (kt + 1) * 32 + quad * 8);
                b1 = *(const bf16x8*)(W4T + n1 * 256 + (kt + 1) * 32 + quad * 8);
            }
            #pragma unroll
            for (int mt = 0; mt < 8; mt++) {
                int m = mt * 16 + l16;
                bf16x8 a = *(const bf16x8*)(sP + m * 512 + ((kt * 64 + quad * 16) ^ ((m & 7) << 4)));
                acc[0][mt] = __builtin_amdgcn_mfma_f32_16x16x32_bf16(a, cb0, acc[0][mt], 0, 0, 0);
                acc[1][mt] = __builtin_amdgcn_mfma_f32_16x16x32_bf16(a, cb1, acc[1][mt], 0, 0, 0);
            }
        }
    }
    __syncthreads();   // all feat4 reads done before feat5 overwrite
    // feat5 = relu(acc + b4) -> sP
    #pragma unroll
    for (int j = 0; j < 2; j++) {
        int n = (wave * 2 + j) * 16 + l16;
        float bias = sb4[n];
        #pragma unroll
        for (int mt = 0; mt < 8; mt++)
            #pragma unroll
            for (int r = 0; r < 4; r++) {
                int m = mt * 16 + quad * 4 + r;
                float v = fmaxf(acc[j][mt][r] + bias, 0.f);
                *(unsigned short*)(sP + m * 512 + ((2 * n) ^ ((m & 7) << 4))) = f2bf(v);
            }
    }
    __syncthreads();
    // segmented max: c = tid&255, sub = tid>>8 walks 64 rows; interior -> store
    {
        int c = tid & 255, r0 = (tid >> 8) * 64;
        int cur = -1; float vmax = 0.f; int segStart = r0;
        for (int r = r0; r < r0 + 64; r++) {
            int v = sVox[r];
            float f = bf2f(*(const unsigned short*)(sP + r * 512 + ((2 * c) ^ ((r & 7) << 4))));
            if (v != cur) {
                if (cur >= 0) {
                    if (segStart > r0)
                        vox2acc[(size_t)cur * 256 + c] = __float_as_uint(vmax);
                    else
                        atomicMax(vox2acc + (size_t)cur * 256 + c, __float_as_uint(vmax));
                }
                cur = v; vmax = f; segStart = r;
            } else vmax = fmaxf(vmax, f);
        }
        if (cur >= 0)
            atomicMax(vox2acc + (size_t)cur * 256 + c, __float_as_uint(vmax));
    }
}

// ---------------------------------------------------------------------------
// Final voxel MLP: out = relu(in @ Wv2 + bv2); safe for in == out.
// ---------------------------------------------------------------------------
__global__ __launch_bounds__(256) void kvox_final(
    const float* __restrict__ in, const unsigned short* __restrict__ WT,
    const float* __restrict__ bias, float* __restrict__ outp)
{
    __shared__ __align__(16) char sA[64 * 512];
    __shared__ float sb[256];
    const f32x4 fzero = {0.f, 0.f, 0.f, 0.f};
    int tid = threadIdx.x;
    int vb = blockIdx.x * 64;
    sb[tid] = bias[tid];
    #pragma unroll
    for (int it = 0; it < 16; it++) {
        int i = tid + 256 * it;
        int m = i >> 6, kq = i & 63;
        float4 f = ((const float4*)(in + (size_t)(vb + m) * 256))[kq];
        uint2 p;
        p.x = (unsigned)f2bf(f.x) | ((unsigned)f2bf(f.y) << 16);
        p.y = (unsigned)f2bf(f.z) | ((unsigned)f2bf(f.w) << 16);
        *(uint2*)(sA + m * 512 + ((8 * kq) ^ ((m & 7) << 4))) = p;
    }
    __syncthreads();
    int wave = tid >> 6, lane = tid & 63, quad = lane >> 4, l16 = lane & 15;
    f32x4 acc[4][4];
    #pragma unroll
    for (int j = 0; j < 4; j++)
        #pragma unroll
        for (int mt = 0; mt < 4; mt++) acc[j][mt] = fzero;
    #pragma unroll 1
    for (int kt = 0; kt < 8; kt++) {
        bf16x8 a[4];
        #pragma unroll
        for (int mt = 0; mt < 4; mt++) {
            int m = mt * 16 + l16;
            a[mt] = *(const bf16x8*)(sA + m * 512 + ((kt * 64 + quad * 16) ^ ((m & 7) << 4)));
        }
        #pragma unroll
        for (int j = 0; j < 4; j++) {
            int n = (wave * 4 + j) * 16 + l16;
            bf16x8 b = *(const bf16x8*)(WT + n * 256 + kt * 32 + quad * 8);
            #pragma unroll
            for (int mt = 0; mt < 4; mt++)
                acc[j][mt] = __builtin_amdgcn_mfma_f32_16x16x32_bf16(a[mt], b, acc[j][mt], 0, 0, 0);
        }
    }
    #pragma unroll
    for (int j = 0; j < 4; j++) {
        int n = (wave * 4 + j) * 16 + l16;
        float bi = sb[n];
        #pragma unroll
        for (int mt = 0; mt < 4; mt++)
            #pragma unroll
            for (int r = 0; r < 4; r++) {
                int m = mt * 16 + quad * 4 + r;
                outp[(size_t)(vb + m) * 256 + n] = fmaxf(acc[j][mt][r] + bi, 0.f);
            }
    }
}

extern "C" void kernel_launch(void* const* d_in, const int* in_sizes, int n_in,
                              void* d_out, int out_size, void* d_ws, size_t ws_size,
                              hipStream_t stream) {
    const float* inp  = (const float*)d_in[0];
    const int*   idx  = (const int*)d_in[1];
    const float* W1   = (const float*)d_in[2];
    const float* b1   = (const float*)d_in[3];
    const float* W2   = (const float*)d_in[4];
    const float* b2   = (const float*)d_in[5];
    const float* Wv1  = (const float*)d_in[6];
    const float* bv1  = (const float*)d_in[7];
    const float* W3   = (const float*)d_in[8];
    const float* b3   = (const float*)d_in[9];
    const float* W4   = (const float*)d_in[10];
    const float* b4   = (const float*)d_in[11];
    const float* Wv2  = (const float*)d_in[12];
    const float* bv2  = (const float*)d_in[13];

    // workspace layout — ~37 MB (voxB aliases vox1acc; vox2acc lives in d_out)
    char* ws = (char*)d_ws;
    size_t off = 0;
    unsigned int*   vox1acc = (unsigned int*)(ws + off);   off += (size_t)NVOX * 128 * 4;  // 32 MB
    unsigned int*   counts  = (unsigned int*)(ws + off);   off += (size_t)NVOX * 4;
    unsigned int*   cursor  = (unsigned int*)(ws + off);   off += (size_t)NVOX * 4;
    int*            order   = (int*)(ws + off);            off += (size_t)N_PTS * 4;
    int*            svox    = (int*)(ws + off);            off += (size_t)N_PTS * 4;
    unsigned short* wsW     = (unsigned short*)(ws + off); off += (size_t)W_TOTAL * 2;

    const unsigned short* W1T  = wsW + WOFF_W1T;
    const unsigned short* W2T  = wsW + WOFF_W2T;
    const unsigned short* Wv1T = wsW + WOFF_WV1T;
    const unsigned short* W3aT = wsW + WOFF_W3AT;
    const unsigned short* W3bT = wsW + WOFF_W3BT;
    const unsigned short* W4T  = wsW + WOFF_W4T;
    const unsigned short* Wv2T = wsW + WOFF_WV2T;

    unsigned short* voxB = (unsigned short*)vox1acc;       // [V][256] bf16, in-place
    unsigned int* vox2acc = (unsigned int*)d_out;          // [V][256] — aliased with output

    hipMemsetAsync(vox1acc, 0, (size_t)NVOX * 128 * 4 + (size_t)NVOX * 4, stream); // +counts
    hipMemsetAsync(vox2acc, 0, (size_t)NVOX * 256 * 4, stream);

    prep_all<<<(W_TOTAL + 255) / 256, 256, 0, stream>>>(W1, W2, Wv1, W3, W4, Wv2, wsW);

    s_hist<<<(N_PTS + 255) / 256, 256, 0, stream>>>(idx, counts);
    s_scan<<<1, 1024, 0, stream>>>(counts, cursor);
    s_scatter<<<(N_PTS + 255) / 256, 256, 0, stream>>>(idx, cursor, order, svox);

    k1_points<<<K1_TILES, 256, 0, stream>>>(inp, order, svox, W1T, b1, W2T, b2, vox1acc);
    kvox2<<<NVOX / 64, 256, 0, stream>>>((const float*)vox1acc, Wv1T, bv1, W3aT, voxB);
    k3_heavy<<<K3_TILES, 512, 0, stream>>>(inp, order, svox, W1T, b1, W2T, b2, voxB,
                                           W3bT, b3, W4T, b4, vox2acc);
    kvox_final<<<NVOX / 64, 256, 0, stream>>>((const float*)vox2acc, Wv2T, bv2,
                                              (float*)d_out);
}

// Round 8
// 662.781 us; speedup vs baseline: 1.0706x; 1.0706x over previous
//
#include <hip/hip_runtime.h>
#include <hip/hip_bf16.h>
#include <stdint.h>

#define N_PTS 500000
#define NVOX  65536
#define K1_TILES ((N_PTS + 127) / 128)   // 3907
#define K3_TILES ((N_PTS + 63) / 64)     // 7813  (M=64 per block, 256 threads)

typedef __attribute__((ext_vector_type(8))) short bf16x8;   // 8 x bf16 (4 VGPRs)
typedef __attribute__((ext_vector_type(4))) float f32x4;    // MFMA accumulator

__device__ inline unsigned short f2bf(float f) {
    union { float f; unsigned int u; } v; v.f = f;
    unsigned int r = v.u + 0x7FFFu + ((v.u >> 16) & 1u);   // RNE
    return (unsigned short)(r >> 16);
}
__device__ inline float bf2f(unsigned short h) {
    return __uint_as_float((unsigned int)h << 16);
}

// --------- fused weight prep: all transposes into one contiguous region ----
#define WOFF_W1T   0
#define WOFF_W2T   2048
#define WOFF_WV1T  10240
#define WOFF_W3AT  26624
#define WOFF_W3BT  59392
#define WOFF_W4T   92160
#define WOFF_WV2T  157696
#define W_TOTAL    223232

__global__ void prep_all(const float* __restrict__ W1, const float* __restrict__ W2,
                         const float* __restrict__ Wv1, const float* __restrict__ W3,
                         const float* __restrict__ W4, const float* __restrict__ Wv2,
                         unsigned short* __restrict__ dst) {
    int i = blockIdx.x * 256 + threadIdx.x;
    if (i >= W_TOTAL) return;
    int o = i;
    if (o < 2048) {                       // W1T: [64][32], pad k
        int n = o >> 5, k = o & 31;
        dst[i] = (k < 6) ? f2bf(W1[k * 64 + n]) : (unsigned short)0;
    } else if ((o -= 2048) < 8192) {      // W2T: K=64 Nn=128
        int n = o >> 6, k = o & 63;
        dst[i] = f2bf(W2[k * 128 + n]);
    } else if ((o -= 8192) < 16384) {     // Wv1T: K=128 Nn=128
        int n = o >> 7, k = o & 127;
        dst[i] = f2bf(Wv1[k * 128 + n]);
    } else if ((o -= 16384) < 32768) {    // W3aT: K=128 Nn=256 k0=0
        int n = o >> 7, k = o & 127;
        dst[i] = f2bf(W3[k * 256 + n]);
    } else if ((o -= 32768) < 32768) {    // W3bT: K=128 Nn=256 k0=128
        int n = o >> 7, k = o & 127;
        dst[i] = f2bf(W3[(k + 128) * 256 + n]);
    } else if ((o -= 32768) < 65536) {    // W4T: K=256 Nn=256
        int n = o >> 8, k = o & 255;
        dst[i] = f2bf(W4[k * 256 + n]);
    } else {                              // Wv2T
        o -= 65536;
        int n = o >> 8, k = o & 255;
        dst[i] = f2bf(Wv2[k * 256 + n]);
    }
}

// ------------------------- counting sort by voxel --------------------------
__global__ void s_hist(const int* __restrict__ idx, unsigned int* __restrict__ counts) {
    int p = blockIdx.x * 256 + threadIdx.x;
    if (p < N_PTS) atomicAdd(&counts[idx[p]], 1u);
}

__global__ __launch_bounds__(1024) void s_scan(const unsigned int* __restrict__ counts,
                                               unsigned int* __restrict__ cursor) {
    __shared__ unsigned int sPart[1024];
    int t = threadIdx.x;
    unsigned int sum = 0;
    #pragma unroll 8
    for (int i = 0; i < 64; i++) sum += counts[t * 64 + i];
    sPart[t] = sum;
    __syncthreads();
    for (int d = 1; d < 1024; d <<= 1) {
        unsigned int add = (t >= d) ? sPart[t - d] : 0u;
        __syncthreads();
        sPart[t] += add;
        __syncthreads();
    }
    unsigned int run = (t == 0) ? 0u : sPart[t - 1];
    #pragma unroll 8
    for (int i = 0; i < 64; i++) {
        cursor[t * 64 + i] = run;
        run += counts[t * 64 + i];
    }
}

__global__ void s_scatter(const int* __restrict__ idx, unsigned int* __restrict__ cursor,
                          int* __restrict__ order, int* __restrict__ svox) {
    int p = blockIdx.x * 256 + threadIdx.x;
    if (p < N_PTS) {
        int v = idx[p];
        unsigned int pos = atomicAdd(&cursor[v], 1u);
        order[pos] = p;
        svox[pos] = v;
    }
}

// ---------------------------------------------------------------------------
// K1 (sorted): per 128-sorted-point tile: feat1, feat2 via MFMA; segmented
// max over voxel runs in LDS; interior segments use plain stores (exclusive
// ownership under sort), boundary segments atomicMax -> vox1acc.
// ---------------------------------------------------------------------------
__global__ __launch_bounds__(256) void k1_points(
    const float* __restrict__ inp,
    const int* __restrict__ order, const int* __restrict__ svox,
    const unsigned short* __restrict__ W1T, const float* __restrict__ b1,
    const unsigned short* __restrict__ W2T, const float* __restrict__ b2,
    unsigned int* __restrict__ vox1acc)      // [V][128] fp32-as-uint (zeroed)
{
    __shared__ __align__(16) char sBuf[32 * 1024];
    __shared__ float sb1[64];
    __shared__ float sb2[128];
    __shared__ int   sVox[128];
    char* sIn = sBuf;                // [128][32] bf16, row 64B,  swz (m&3)<<4
    char* sF1 = sBuf + 8 * 1024;     // [128][64] bf16, row 128B, swz (m&7)<<4
    char* sF2 = sBuf;                // [128][128] bf16, row 256B, swz (m&7)<<4
    const f32x4 fzero = {0.f, 0.f, 0.f, 0.f};
    int tid = threadIdx.x;
    int pbase = blockIdx.x * 128;
    if (tid < 64)       sb1[tid] = b1[tid];
    else if (tid < 192) sb2[tid - 64] = b2[tid - 64];
    if (tid < 128) {
        int i = pbase + tid;
        int pt = -1, v = -1;
        if (i < N_PTS) { pt = order[i]; v = svox[i]; }
        sVox[tid] = v;
        uint4 g0 = {0u, 0u, 0u, 0u};
        if (pt >= 0) {
            const float* x = inp + (size_t)pt * 6;
            g0.x = (unsigned)f2bf(x[0]) | ((unsigned)f2bf(x[1]) << 16);
            g0.y = (unsigned)f2bf(x[2]) | ((unsigned)f2bf(x[3]) << 16);
            g0.z = (unsigned)f2bf(x[4]) | ((unsigned)f2bf(x[5]) << 16);
        }
        int swz = (tid & 3) << 4;
        char* row = sIn + tid * 64;
        uint4 z = {0u, 0u, 0u, 0u};
        *(uint4*)(row + (0  ^ swz)) = g0;
        *(uint4*)(row + (16 ^ swz)) = z;
        *(uint4*)(row + (32 ^ swz)) = z;
        *(uint4*)(row + (48 ^ swz)) = z;
    }
    __syncthreads();
    int wave = tid >> 6, lane = tid & 63, quad = lane >> 4, l16 = lane & 15;

    // GEMM1: [128][32]@[32][64]
    {
        f32x4 acc1[8];
        #pragma unroll
        for (int mt = 0; mt < 8; mt++) acc1[mt] = fzero;
        int n = wave * 16 + l16;
        bf16x8 b = *(const bf16x8*)(W1T + n * 32 + quad * 8);
        #pragma unroll
        for (int mt = 0; mt < 8; mt++) {
            int m = mt * 16 + l16;
            bf16x8 a = *(const bf16x8*)(sIn + m * 64 + ((quad * 16) ^ ((m & 3) << 4)));
            acc1[mt] = __builtin_amdgcn_mfma_f32_16x16x32_bf16(a, b, acc1[mt], 0, 0, 0);
        }
        float bias = sb1[n];
        #pragma unroll
        for (int mt = 0; mt < 8; mt++)
            #pragma unroll
            for (int r = 0; r < 4; r++) {
                int m = mt * 16 + quad * 4 + r;
                float v = fmaxf(acc1[mt][r] + bias, 0.f);
                *(unsigned short*)(sF1 + m * 128 + ((2 * n) ^ ((m & 7) << 4))) = f2bf(v);
            }
    }
    __syncthreads();
    // GEMM2: [128][64]@[64][128]
    f32x4 acc2[2][8];
    #pragma unroll
    for (int j = 0; j < 2; j++)
        #pragma unroll
        for (int mt = 0; mt < 8; mt++) acc2[j][mt] = fzero;
    #pragma unroll
    for (int kt = 0; kt < 2; kt++) {
        bf16x8 b0 = *(const bf16x8*)(W2T + ((wave * 2 + 0) * 16 + l16) * 64 + kt * 32 + quad * 8);
        bf16x8 b1 = *(const bf16x8*)(W2T + ((wave * 2 + 1) * 16 + l16) * 64 + kt * 32 + quad * 8);
        #pragma unroll
        for (int mt = 0; mt < 8; mt++) {
            int m = mt * 16 + l16;
            bf16x8 a = *(const bf16x8*)(sF1 + m * 128 + ((kt * 64 + quad * 16) ^ ((m & 7) << 4)));
            acc2[0][mt] = __builtin_amdgcn_mfma_f32_16x16x32_bf16(a, b0, acc2[0][mt], 0, 0, 0);
            acc2[1][mt] = __builtin_amdgcn_mfma_f32_16x16x32_bf16(a, b1, acc2[1][mt], 0, 0, 0);
        }
    }
    __syncthreads();   // all sIn/sF1 reads done before sF2 overwrite
    #pragma unroll
    for (int j = 0; j < 2; j++) {
        int n = (wave * 2 + j) * 16 + l16;
        float bias = sb2[n];
        #pragma unroll
        for (int mt = 0; mt < 8; mt++)
            #pragma unroll
            for (int r = 0; r < 4; r++) {
                int m = mt * 16 + quad * 4 + r;
                float v = fmaxf(acc2[j][mt][r] + bias, 0.f);
                *(unsigned short*)(sF2 + m * 256 + ((2 * n) ^ ((m & 7) << 4))) = f2bf(v);
            }
    }
    __syncthreads();
    // segmented max walk; interior segments -> plain store
    {
        int c = tid & 127, r0 = (tid >> 7) * 64;
        int cur = -1; float vmax = 0.f; int segStart = r0;
        for (int r = r0; r < r0 + 64; r++) {
            int v = sVox[r];
            float f = bf2f(*(const unsigned short*)(sF2 + r * 256 + ((2 * c) ^ ((r & 7) << 4))));
            if (v != cur) {
                if (cur >= 0) {
                    if (segStart > r0)
                        vox1acc[(size_t)cur * 128 + c] = __float_as_uint(vmax);
                    else
                        atomicMax(vox1acc + (size_t)cur * 128 + c, __float_as_uint(vmax));
                }
                cur = v; vmax = f; segStart = r;
            } else vmax = fmaxf(vmax, f);
        }
        if (cur >= 0)
            atomicMax(vox1acc + (size_t)cur * 128 + c, __float_as_uint(vmax));
    }
}

// ---------------------------------------------------------------------------
// kvox2 (fused voxel chain): voxA = relu(vox1acc@Wv1+bv1);
// voxB = voxA@W3a (no bias/relu — b3 added in k3). voxB written IN-PLACE over
// vox1acc (block reads its 64 rows to LDS first; same byte range: 512 B/row).
// ---------------------------------------------------------------------------
__global__ __launch_bounds__(256) void kvox2(
    const float* __restrict__ in, const unsigned short* __restrict__ Wv1T,
    const float* __restrict__ bv1, const unsigned short* __restrict__ W3aT,
    unsigned short* __restrict__ voxB)     // [V][256] bf16, aliases `in`
{
    __shared__ __align__(16) char sA[64 * 256];   // [64][128] bf16 input
    __shared__ __align__(16) char sB[64 * 256];   // [64][128] bf16 voxA
    __shared__ float sb[128];
    const f32x4 fzero = {0.f, 0.f, 0.f, 0.f};
    int tid = threadIdx.x;
    int vb = blockIdx.x * 64;
    if (tid < 128) sb[tid] = bv1[tid];
    #pragma unroll
    for (int it = 0; it < 8; it++) {
        int i = tid + 256 * it;
        int m = i >> 5, kq = i & 31;
        float4 f = ((const float4*)(in + (size_t)(vb + m) * 128))[kq];
        uint2 p;
        p.x = (unsigned)f2bf(f.x) | ((unsigned)f2bf(f.y) << 16);
        p.y = (unsigned)f2bf(f.z) | ((unsigned)f2bf(f.w) << 16);
        *(uint2*)(sA + m * 256 + ((8 * kq) ^ ((m & 7) << 4))) = p;
    }
    __syncthreads();
    int wave = tid >> 6, lane = tid & 63, quad = lane >> 4, l16 = lane & 15;
    // GEMM A: voxA = relu([64][128]@[128][128] + bv1)
    {
        f32x4 acc[2][4];
        #pragma unroll
        for (int j = 0; j < 2; j++)
            #pragma unroll
            for (int mt = 0; mt < 4; mt++) acc[j][mt] = fzero;
        #pragma unroll
        for (int kt = 0; kt < 4; kt++) {
            bf16x8 a[4];
            #pragma unroll
            for (int mt = 0; mt < 4; mt++) {
                int m = mt * 16 + l16;
                a[mt] = *(const bf16x8*)(sA + m * 256 + ((kt * 64 + quad * 16) ^ ((m & 7) << 4)));
            }
            #pragma unroll
            for (int j = 0; j < 2; j++) {
                int n = (wave * 2 + j) * 16 + l16;
                bf16x8 b = *(const bf16x8*)(Wv1T + n * 128 + kt * 32 + quad * 8);
                #pragma unroll
                for (int mt = 0; mt < 4; mt++)
                    acc[j][mt] = __builtin_amdgcn_mfma_f32_16x16x32_bf16(a[mt], b, acc[j][mt], 0, 0, 0);
            }
        }
        #pragma unroll
        for (int j = 0; j < 2; j++) {
            int n = (wave * 2 + j) * 16 + l16;
            float bi = sb[n];
            #pragma unroll
            for (int mt = 0; mt < 4; mt++)
                #pragma unroll
                for (int r = 0; r < 4; r++) {
                    int m = mt * 16 + quad * 4 + r;
                    float v = fmaxf(acc[j][mt][r] + bi, 0.f);
                    *(unsigned short*)(sB + m * 256 + ((2 * n) ^ ((m & 7) << 4))) = f2bf(v);
                }
        }
    }
    __syncthreads();
    // GEMM B: voxB = voxA@[128][256]; no bias/relu
    {
        f32x4 acc[4][4];
        #pragma unroll
        for (int j = 0; j < 4; j++)
            #pragma unroll
            for (int mt = 0; mt < 4; mt++) acc[j][mt] = fzero;
        #pragma unroll
        for (int kt = 0; kt < 4; kt++) {
            bf16x8 a[4];
            #pragma unroll
            for (int mt = 0; mt < 4; mt++) {
                int m = mt * 16 + l16;
                a[mt] = *(const bf16x8*)(sB + m * 256 + ((kt * 64 + quad * 16) ^ ((m & 7) << 4)));
            }
            #pragma unroll
            for (int j = 0; j < 4; j++) {
                int n = (wave * 4 + j) * 16 + l16;
                bf16x8 b = *(const bf16x8*)(W3aT + n * 128 + kt * 32 + quad * 8);
                #pragma unroll
                for (int mt = 0; mt < 4; mt++)
                    acc[j][mt] = __builtin_amdgcn_mfma_f32_16x16x32_bf16(a[mt], b, acc[j][mt], 0, 0, 0);
            }
        }
        #pragma unroll
        for (int j = 0; j < 4; j++) {
            int n = (wave * 4 + j) * 16 + l16;
            #pragma unroll
            for (int mt = 0; mt < 4; mt++)
                #pragma unroll
                for (int r = 0; r < 4; r++) {
                    int m = mt * 16 + quad * 4 + r;
                    voxB[(size_t)(vb + m) * 256 + n] = f2bf(acc[j][mt][r]);
                }
        }
    }
}

// ---------------------------------------------------------------------------
// K3 v8: 256 threads (4 waves), M=64/block, __launch_bounds__(256,3):
// 12 waves/CU @ ~170 unified regs/wave — acc[4][4]=64 AGPR + ~80 VGPR, NO
// spills. Carries W3-split (GEMM3' K=128), sorted dedup gather, interior-
// store segmax. LDS: 32 KB arena (sF2/sF1/sIn overlay -> sP) + 3 KB biases.
// ---------------------------------------------------------------------------
__global__ __launch_bounds__(256, 3) void k3_heavy(
    const float* __restrict__ inp,
    const int* __restrict__ order, const int* __restrict__ svox,
    const unsigned short* __restrict__ W1T, const float* __restrict__ b1,
    const unsigned short* __restrict__ W2T, const float* __restrict__ b2,
    const unsigned short* __restrict__ voxB,     // [V][256] bf16
    const unsigned short* __restrict__ W3bT, const float* __restrict__ b3,
    const unsigned short* __restrict__ W4T, const float* __restrict__ b4,
    unsigned int* __restrict__ vox2acc)          // [V][256] fp32-as-uint (zeroed)
{
    __shared__ __align__(16) char sBuf[32 * 1024];
    __shared__ float sb1[64];
    __shared__ float sb2[128];
    __shared__ float sb3[256];
    __shared__ float sb4[256];
    __shared__ int   sVox[64];
    char* sF2 = sBuf;                 // [64][128] bf16, row 256B  (dies after GEMM3')
    char* sF1 = sBuf + 16 * 1024;     // [64][64]  bf16, row 128B  (phase 1-2)
    char* sIn = sBuf + 24 * 1024;     // [64][32]  bf16, row 64B   (phase 0-1)
    char* sP  = sBuf;                 // [64][256] bf16, row 512B  (gather onward)
    const f32x4 fzero = {0.f, 0.f, 0.f, 0.f};
    int tid = threadIdx.x;
    int pbase = blockIdx.x * 64;
    sb3[tid] = b3[tid];
    sb4[tid] = b4[tid];
    if (tid < 64)  sb1[tid] = b1[tid];
    if (tid < 128) sb2[tid] = b2[tid];
    if (tid < 64) {
        int i = pbase + tid;
        int pt = -1, v = -1;
        if (i < N_PTS) { pt = order[i]; v = svox[i]; }
        sVox[tid] = v;
        uint4 g0 = {0u, 0u, 0u, 0u};
        if (pt >= 0) {
            const float* x = inp + (size_t)pt * 6;
            g0.x = (unsigned)f2bf(x[0]) | ((unsigned)f2bf(x[1]) << 16);
            g0.y = (unsigned)f2bf(x[2]) | ((unsigned)f2bf(x[3]) << 16);
            g0.z = (unsigned)f2bf(x[4]) | ((unsigned)f2bf(x[5]) << 16);
        }
        int swz = (tid & 3) << 4;
        char* row = sIn + tid * 64;
        uint4 z = {0u, 0u, 0u, 0u};
        *(uint4*)(row + (0  ^ swz)) = g0;
        *(uint4*)(row + (16 ^ swz)) = z;
        *(uint4*)(row + (32 ^ swz)) = z;
        *(uint4*)(row + (48 ^ swz)) = z;
    }
    __syncthreads();
    int wave = tid >> 6, lane = tid & 63, quad = lane >> 4, l16 = lane & 15;

    // GEMM1: feat1 = relu([64][32]@[32][64] + b1); wave owns n-tile `wave`
    {
        f32x4 acc1[4];
        #pragma unroll
        for (int mt = 0; mt < 4; mt++) acc1[mt] = fzero;
        int n = wave * 16 + l16;
        bf16x8 b = *(const bf16x8*)(W1T + n * 32 + quad * 8);
        #pragma unroll
        for (int mt = 0; mt < 4; mt++) {
            int m = mt * 16 + l16;
            bf16x8 a = *(const bf16x8*)(sIn + m * 64 + ((quad * 16) ^ ((m & 3) << 4)));
            acc1[mt] = __builtin_amdgcn_mfma_f32_16x16x32_bf16(a, b, acc1[mt], 0, 0, 0);
        }
        float bias = sb1[n];
        #pragma unroll
        for (int mt = 0; mt < 4; mt++)
            #pragma unroll
            for (int r = 0; r < 4; r++) {
                int m = mt * 16 + quad * 4 + r;
                float v = fmaxf(acc1[mt][r] + bias, 0.f);
                *(unsigned short*)(sF1 + m * 128 + ((2 * n) ^ ((m & 7) << 4))) = f2bf(v);
            }
    }
    __syncthreads();
    // GEMM2: feat2 = relu([64][64]@[64][128] + b2); wave owns n-tiles 2w,2w+1
    {
        f32x4 acc2[2][4];
        #pragma unroll
        for (int j = 0; j < 2; j++)
            #pragma unroll
            for (int mt = 0; mt < 4; mt++) acc2[j][mt] = fzero;
        #pragma unroll
        for (int kt = 0; kt < 2; kt++) {
            bf16x8 b0 = *(const bf16x8*)(W2T + ((wave * 2 + 0) * 16 + l16) * 64 + kt * 32 + quad * 8);
            bf16x8 b1 = *(const bf16x8*)(W2T + ((wave * 2 + 1) * 16 + l16) * 64 + kt * 32 + quad * 8);
            #pragma unroll
            for (int mt = 0; mt < 4; mt++) {
                int m = mt * 16 + l16;
                bf16x8 a = *(const bf16x8*)(sF1 + m * 128 + ((kt * 64 + quad * 16) ^ ((m & 7) << 4)));
                acc2[0][mt] = __builtin_amdgcn_mfma_f32_16x16x32_bf16(a, b0, acc2[0][mt], 0, 0, 0);
                acc2[1][mt] = __builtin_amdgcn_mfma_f32_16x16x32_bf16(a, b1, acc2[1][mt], 0, 0, 0);
            }
        }
        #pragma unroll
        for (int j = 0; j < 2; j++) {
            int n = (wave * 2 + j) * 16 + l16;
            float bias = sb2[n];
            #pragma unroll
            for (int mt = 0; mt < 4; mt++)
                #pragma unroll
                for (int r = 0; r < 4; r++) {
                    int m = mt * 16 + quad * 4 + r;
                    float v = fmaxf(acc2[j][mt][r] + bias, 0.f);
                    *(unsigned short*)(sF2 + m * 256 + ((2 * n) ^ ((m & 7) << 4))) = f2bf(v);
                }
        }
    }
    __syncthreads();   // sF1/sIn dead; sF2 complete

    // GEMM3': [64][128] @ [128][256]; wave owns 4 n-tiles x 4 m-tiles
    f32x4 acc[4][4];
    #pragma unroll
    for (int j = 0; j < 4; j++)
        #pragma unroll
        for (int mt = 0; mt < 4; mt++) acc[j][mt] = fzero;
    #pragma unroll 1
    for (int kt = 0; kt < 4; kt++) {
        bf16x8 a[4];
        #pragma unroll
        for (int mt = 0; mt < 4; mt++) {
            int m = mt * 16 + l16;
            a[mt] = *(const bf16x8*)(sF2 + m * 256 + ((kt * 64 + quad * 16) ^ ((m & 7) << 4)));
        }
        #pragma unroll
        for (int j = 0; j < 4; j++) {
            int n = (wave * 4 + j) * 16 + l16;
            bf16x8 b = *(const bf16x8*)(W3bT + n * 128 + kt * 32 + quad * 8);
            #pragma unroll
            for (int mt = 0; mt < 4; mt++)
                acc[j][mt] = __builtin_amdgcn_mfma_f32_16x16x32_bf16(a[mt], b, acc[j][mt], 0, 0, 0);
        }
    }
    __syncthreads();   // sF2 reads complete — arena becomes sP
    // gather voxB rows -> sP [64][256] (sorted -> dedup, L2 hits)
    #pragma unroll
    for (int it = 0; it < 8; it++) {
        int i = tid + 256 * it;
        int m = i >> 5, c = i & 31;
        int vv = sVox[m];
        uint4 val = {0u, 0u, 0u, 0u};
        if (vv >= 0)
            val = ((const uint4*)(voxB + (size_t)vv * 256))[c];
        *(uint4*)(sP + m * 512 + ((c * 16) ^ ((m & 7) << 4))) = val;
    }
    __syncthreads();
    // feat4 = relu(acc + b3 + voxpart) -> sP in-place
    #pragma unroll
    for (int j = 0; j < 4; j++) {
        int n = (wave * 4 + j) * 16 + l16;
        float bias = sb3[n];
        #pragma unroll
        for (int mt = 0; mt < 4; mt++)
            #pragma unroll
            for (int r = 0; r < 4; r++) {
                int m = mt * 16 + quad * 4 + r;
                char* p = sP + m * 512 + ((2 * n) ^ ((m & 7) << 4));
                float vox = bf2f(*(const unsigned short*)p);
                float v = fmaxf(acc[j][mt][r] + bias + vox, 0.f);
                *(unsigned short*)p = f2bf(v);
            }
    }
    __syncthreads();
    #pragma unroll
    for (int j = 0; j < 4; j++)
        #pragma unroll
        for (int mt = 0; mt < 4; mt++) acc[j][mt] = fzero;
    // GEMM4: [64][256] @ [256][256]
    #pragma unroll 1
    for (int kt = 0; kt < 8; kt++) {
        bf16x8 a[4];
        #pragma unroll
        for (int mt = 0; mt < 4; mt++) {
            int m = mt * 16 + l16;
            a[mt] = *(const bf16x8*)(sP + m * 512 + ((kt * 64 + quad * 16) ^ ((m & 7) << 4)));
        }
        #pragma unroll
        for (int j = 0; j < 4; j++) {
            int n = (wave * 4 + j) * 16 + l16;
            bf16x8 b = *(const bf16x8*)(W4T + n * 256 + kt * 32 + quad * 8);
            #pragma unroll
            for (int mt = 0; mt < 4; mt++)
                acc[j][mt] = __builtin_amdgcn_mfma_f32_16x16x32_bf16(a[mt], b, acc[j][mt], 0, 0, 0);
        }
    }
    __syncthreads();   // all feat4 reads done before feat5 overwrite
    // feat5 = relu(acc + b4) -> sP
    #pragma unroll
    for (int j = 0; j < 4; j++) {
        int n = (wave * 4 + j) * 16 + l16;
        float bias = sb4[n];
        #pragma unroll
        for (int mt = 0; mt < 4; mt++)
            #pragma unroll
            for (int r = 0; r < 4; r++) {
                int m = mt * 16 + quad * 4 + r;
                float v = fmaxf(acc[j][mt][r] + bias, 0.f);
                *(unsigned short*)(sP + m * 512 + ((2 * n) ^ ((m & 7) << 4))) = f2bf(v);
            }
    }
    __syncthreads();
    // segmented max: c = tid (256 cols), 64 rows; interior -> plain store
    {
        int c = tid;
        int cur = -1; float vmax = 0.f; int segStart = 0;
        for (int r = 0; r < 64; r++) {
            int v = sVox[r];
            float f = bf2f(*(const unsigned short*)(sP + r * 512 + ((2 * c) ^ ((r & 7) << 4))));
            if (v != cur) {
                if (cur >= 0) {
                    if (segStart > 0)
                        vox2acc[(size_t)cur * 256 + c] = __float_as_uint(vmax);
                    else
                        atomicMax(vox2acc + (size_t)cur * 256 + c, __float_as_uint(vmax));
                }
                cur = v; vmax = f; segStart = r;
            } else vmax = fmaxf(vmax, f);
        }
        if (cur >= 0)
            atomicMax(vox2acc + (size_t)cur * 256 + c, __float_as_uint(vmax));
    }
}

// ---------------------------------------------------------------------------
// Final voxel MLP: out = relu(in @ Wv2 + bv2); safe for in == out.
// ---------------------------------------------------------------------------
__global__ __launch_bounds__(256) void kvox_final(
    const float* __restrict__ in, const unsigned short* __restrict__ WT,
    const float* __restrict__ bias, float* __restrict__ outp)
{
    __shared__ __align__(16) char sA[64 * 512];
    __shared__ float sb[256];
    const f32x4 fzero = {0.f, 0.f, 0.f, 0.f};
    int tid = threadIdx.x;
    int vb = blockIdx.x * 64;
    sb[tid] = bias[tid];
    #pragma unroll
    for (int it = 0; it < 16; it++) {
        int i = tid + 256 * it;
        int m = i >> 6, kq = i & 63;
        float4 f = ((const float4*)(in + (size_t)(vb + m) * 256))[kq];
        uint2 p;
        p.x = (unsigned)f2bf(f.x) | ((unsigned)f2bf(f.y) << 16);
        p.y = (unsigned)f2bf(f.z) | ((unsigned)f2bf(f.w) << 16);
        *(uint2*)(sA + m * 512 + ((8 * kq) ^ ((m & 7) << 4))) = p;
    }
    __syncthreads();
    int wave = tid >> 6, lane = tid & 63, quad = lane >> 4, l16 = lane & 15;
    f32x4 acc[4][4];
    #pragma unroll
    for (int j = 0; j < 4; j++)
        #pragma unroll
        for (int mt = 0; mt < 4; mt++) acc[j][mt] = fzero;
    #pragma unroll 1
    for (int kt = 0; kt < 8; kt++) {
        bf16x8 a[4];
        #pragma unroll
        for (int mt = 0; mt < 4; mt++) {
            int m = mt * 16 + l16;
            a[mt] = *(const bf16x8*)(sA + m * 512 + ((kt * 64 + quad * 16) ^ ((m & 7) << 4)));
        }
        #pragma unroll
        for (int j = 0; j < 4; j++) {
            int n = (wave * 4 + j) * 16 + l16;
            bf16x8 b = *(const bf16x8*)(WT + n * 256 + kt * 32 + quad * 8);
            #pragma unroll
            for (int mt = 0; mt < 4; mt++)
                acc[j][mt] = __builtin_amdgcn_mfma_f32_16x16x32_bf16(a[mt], b, acc[j][mt], 0, 0, 0);
        }
    }
    #pragma unroll
    for (int j = 0; j < 4; j++) {
        int n = (wave * 4 + j) * 16 + l16;
        float bi = sb[n];
        #pragma unroll
        for (int mt = 0; mt < 4; mt++)
            #pragma unroll
            for (int r = 0; r < 4; r++) {
                int m = mt * 16 + quad * 4 + r;
                outp[(size_t)(vb + m) * 256 + n] = fmaxf(acc[j][mt][r] + bi, 0.f);
            }
    }
}

extern "C" void kernel_launch(void* const* d_in, const int* in_sizes, int n_in,
                              void* d_out, int out_size, void* d_ws, size_t ws_size,
                              hipStream_t stream) {
    const float* inp  = (const float*)d_in[0];
    const int*   idx  = (const int*)d_in[1];
    const float* W1   = (const float*)d_in[2];
    const float* b1   = (const float*)d_in[3];
    const float* W2   = (const float*)d_in[4];
    const float* b2   = (const float*)d_in[5];
    const float* Wv1  = (const float*)d_in[6];
    const float* bv1  = (const float*)d_in[7];
    const float* W3   = (const float*)d_in[8];
    const float* b3   = (const float*)d_in[9];
    const float* W4   = (const float*)d_in[10];
    const float* b4   = (const float*)d_in[11];
    const float* Wv2  = (const float*)d_in[12];
    const float* bv2  = (const float*)d_in[13];

    // workspace layout — ~37 MB (voxB aliases vox1acc; vox2acc lives in d_out)
    char* ws = (char*)d_ws;
    size_t off = 0;
    unsigned int*   vox1acc = (unsigned int*)(ws + off);   off += (size_t)NVOX * 128 * 4;  // 32 MB
    unsigned int*   counts  = (unsigned int*)(ws + off);   off += (size_t)NVOX * 4;
    unsigned int*   cursor  = (unsigned int*)(ws + off);   off += (size_t)NVOX * 4;
    int*            order   = (int*)(ws + off);            off += (size_t)N_PTS * 4;
    int*            svox    = (int*)(ws + off);            off += (size_t)N_PTS * 4;
    unsigned short* wsW     = (unsigned short*)(ws + off); off += (size_t)W_TOTAL * 2;

    const unsigned short* W1T  = wsW + WOFF_W1T;
    const unsigned short* W2T  = wsW + WOFF_W2T;
    const unsigned short* Wv1T = wsW + WOFF_WV1T;
    const unsigned short* W3aT = wsW + WOFF_W3AT;
    const unsigned short* W3bT = wsW + WOFF_W3BT;
    const unsigned short* W4T  = wsW + WOFF_W4T;
    const unsigned short* Wv2T = wsW + WOFF_WV2T;

    unsigned short* voxB = (unsigned short*)vox1acc;       // [V][256] bf16, in-place
    unsigned int* vox2acc = (unsigned int*)d_out;          // [V][256] — aliased with output

    hipMemsetAsync(vox1acc, 0, (size_t)NVOX * 128 * 4 + (size_t)NVOX * 4, stream); // +counts
    hipMemsetAsync(vox2acc, 0, (size_t)NVOX * 256 * 4, stream);

    prep_all<<<(W_TOTAL + 255) / 256, 256, 0, stream>>>(W1, W2, Wv1, W3, W4, Wv2, wsW);

    s_hist<<<(N_PTS + 255) / 256, 256, 0, stream>>>(idx, counts);
    s_scan<<<1, 1024, 0, stream>>>(counts, cursor);
    s_scatter<<<(N_PTS + 255) / 256, 256, 0, stream>>>(idx, cursor, order, svox);

    k1_points<<<K1_TILES, 256, 0, stream>>>(inp, order, svox, W1T, b1, W2T, b2, vox1acc);
    kvox2<<<NVOX / 64, 256, 0, stream>>>((const float*)vox1acc, Wv1T, bv1, W3aT, voxB);
    k3_heavy<<<K3_TILES, 256, 0, stream>>>(inp, order, svox, W1T, b1, W2T, b2, voxB,
                                           W3bT, b3, W4T, b4, vox2acc);
    kvox_final<<<NVOX / 64, 256, 0, stream>>>((const float*)vox2acc, Wv2T, bv2,
                                              (float*)d_out);
}